// Round 20
// baseline (111.598 us; speedup 1.0000x reference)
//
#include <hip/hip_runtime.h>
#include <hip/hip_bf16.h>
#include <stdint.h>

// C = (B,16,16): diag (k,k)=sigmoid(x·Wd[k]+bd[k]); off (i,j)=-softplus(x·Wo[r]+bo[r])
// Permuted GEMM out[b][c], c=i*16+j. M=65536 N=256 K=1024, bf16 MFMA 16x16x32.
// R20: BK=64 -> x read in 256B-per-row granules (vs 128B in R1-R19); tests the
// DRAM-granularity ceiling hypothesis (all prior kernels converge to 3.15 TB/s
// = 50% of sequential copy = classic 128B-scatter efficiency). BM=128, 512
// blocks x 512 thr (8 waves 2Mx4N). A fp32 chunks 32KB ring-2 via gload_lds
// (pre-swizzled source, (row&15)<<4 XOR); B 32KB ring-2 from R7-verified
// (c&7)<<4 image. Loads issued at chunk top, drained at chunk bottom (cover =
// full ~3200cyc chunk >> 900cyc HBM latency). LDS 128KB -> 1 block/CU.

typedef __bf16 bf16x8 __attribute__((ext_vector_type(8)));
typedef float f32x4 __attribute__((ext_vector_type(4)));

#define THREADS 512
#define BM 128
#define NCHUNK 16                  // K chunks of 64
#define CIMG 32768                 // per-chunk B image: 256 cols x 64 k x 2B
#define WBYTES (CIMG * NCHUNK)     // 512 KiB

#define ASLOT 32768                // A chunk: 128 rows x 256B fp32 (swizzled)
#define BBASE 65536                // A slots @0,32K ; B slots @64K,96K
#define BSLOT 32768
#define SMEM_SZ 131072             // 128 KiB -> 1 block/CU

__device__ __forceinline__ unsigned bf_rtne(unsigned u) {
  return (u + 0x7fffu + ((u >> 16) & 1u)) >> 16;
}
__device__ __forceinline__ unsigned pack2(float lo, float hi) {
  return bf_rtne(__float_as_uint(lo)) | (bf_rtne(__float_as_uint(hi)) << 16);
}
// A-fragment pack: scalar casts -> compiler emits v_cvt_pk_bf16_f32 (RTNE)
__device__ __forceinline__ bf16x8 packfrag(const f32x4& a, const f32x4& b) {
  bf16x8 r;
  r[0] = (__bf16)a[0]; r[1] = (__bf16)a[1]; r[2] = (__bf16)a[2]; r[3] = (__bf16)a[3];
  r[4] = (__bf16)b[0]; r[5] = (__bf16)b[1]; r[6] = (__bf16)b[2]; r[7] = (__bf16)b[3];
  return r;
}
__device__ __forceinline__ void gload_lds16(const void* g, void* l) {
  __builtin_amdgcn_global_load_lds(
      (const __attribute__((address_space(1))) unsigned int*)g,
      (__attribute__((address_space(3))) unsigned int*)l, 16, 0, 0);
}

// B image per chunk (R7-verified): byte(c,k6) = c*128 + ((k6*2) ^ ((c&7)<<4))
__global__ void prep_kernel(const float* __restrict__ Wd, const float* __restrict__ bd,
                            const float* __restrict__ Wo, const float* __restrict__ bo,
                            char* __restrict__ wbuf, float* __restrict__ bias) {
  const int c = blockIdx.x;    // 0..255 output col
  const int t = threadIdx.x;   // 0..255, 4 consecutive k each
  const int i = c >> 4, j = c & 15;
  const float* src;
  float b;
  if (i == j) { src = Wd + i * 1024; b = bd[i]; }
  else { int r = i * 15 + (j < i ? j : j - 1); src = Wo + r * 1024; b = bo[r]; }
  if (t == 0) bias[c] = b;
  const int kk = t * 4;
  const int chunk = kk >> 6, k6 = kk & 63;
  float4 v = *reinterpret_cast<const float4*>(src + kk);
  uint2 h;
  h.x = pack2(v.x, v.y);
  h.y = pack2(v.z, v.w);
  const unsigned off = (unsigned)(c * 128 + ((k6 * 2) ^ ((c & 7) << 4)));
  *reinterpret_cast<uint2*>(wbuf + chunk * CIMG + off) = h;
}

__global__ __launch_bounds__(THREADS) void cap_main(
    const float* __restrict__ x, const char* __restrict__ wbuf,
    const float* __restrict__ bias, float* __restrict__ out) {
  __shared__ char smem[SMEM_SZ];

  const int tid = threadIdx.x;
  const int wid = tid >> 6;
  const int lane = tid & 63;
  const int l15 = lane & 15;
  const int l4 = lane >> 4;
  const int wm = wid >> 2;       // 0..1: rows wm*64..+63
  const int wn = wid & 3;        // 0..3: cols wn*64..+63

  const size_t blkRow = (size_t)blockIdx.x * BM;

  // ---- A staging map (4 insts/thread; 512 thr x 16B x 4 = 32 KB chunk) ----
  // inst i: row = i*32 + (tid>>4); 16 lanes x 16B = 256B contiguous per row.
  // LDS byte(row,u16) = row*256 + (u*16 ^ ((row&15)<<4)) -> pre-swizzle source.
  const unsigned acol = (unsigned)(((tid & 15) * 16) ^ ((((tid >> 4) & 15)) << 4));
  const char* asrc[4];
  unsigned adst[4];
#pragma unroll
  for (int i = 0; i < 4; ++i) {
    const int row = i * 32 + (tid >> 4);
    asrc[i] = (const char*)(x + (blkRow + (size_t)row) * 1024) + acol;
    adst[i] = (unsigned)(i * 8192 + tid * 16);
  }

  // ---- fragment read bases ----
  const unsigned swA = (unsigned)(l15 << 4);          // (row&15)<<4, row%16==l15
  const unsigned swB = (unsigned)((l15 & 7) << 4);    // (c&7)<<4,  c%8==l15%8
  // B frag: col c = wn*64+n*16+l15 -> byte = c*128 + ((ks*64 + l4*16) ^ swB)
  const unsigned bcol = (unsigned)((wn * 64 + l15) * 128);

  f32x4 acc[4][4];
#pragma unroll
  for (int m = 0; m < 4; ++m)
#pragma unroll
    for (int n = 0; n < 4; ++n) acc[m][n] = (f32x4){0.f, 0.f, 0.f, 0.f};

#define STAGE_A(CH, SL)                                                        \
  {                                                                            \
    _Pragma("unroll") for (int i = 0; i < 4; ++i)                              \
        gload_lds16(asrc[i] + (CH) * 256, smem + (SL) + adst[i]);              \
  }
#define STAGE_B(CH, SL)                                                        \
  {                                                                            \
    const char* wsp = wbuf + (CH) * CIMG;                                      \
    _Pragma("unroll") for (int i = 0; i < 4; ++i)                              \
        gload_lds16(wsp + i * 8192 + tid * 16,                                 \
                    smem + BBASE + (SL) + i * 8192 + tid * 16);                \
  }

  // ---- prologue: chunk 0 into slot 0; drain; barrier ----
  STAGE_A(0, 0);
  STAGE_B(0, 0);
  asm volatile("s_waitcnt vmcnt(0)" ::: "memory");
  __builtin_amdgcn_s_barrier();

  for (int t = 0; t < NCHUNK; ++t) {
    const unsigned sc = (unsigned)(t & 1);          // current slot
    const unsigned sn = sc ^ 1u;                    // next slot

    // issue next chunk's loads FIRST (cover = this whole chunk's compute)
    const int tn = (t + 1 < NCHUNK) ? t + 1 : NCHUNK - 1;
    STAGE_B(tn, sn * BSLOT);
    STAGE_A(tn, sn * ASLOT);

    const char* Ac = smem + sc * ASLOT;
    const char* Bc = smem + BBASE + sc * BSLOT;

    // 2 MFMA sub-steps (ks = k-halves of the 64-k chunk)
#pragma unroll
    for (int ks = 0; ks < 2; ++ks) {
      bf16x8 af[4], bfr[4];
#pragma unroll
      for (int m = 0; m < 4; ++m) {
        const unsigned rb = (unsigned)((wm * 64 + m * 16 + l15) * 256);
        f32x4 u0 = *reinterpret_cast<const f32x4*>(
            Ac + rb + ((ks * 128 + l4 * 32) ^ swA));
        f32x4 u1 = *reinterpret_cast<const f32x4*>(
            Ac + rb + ((ks * 128 + l4 * 32 + 16) ^ swA));
        af[m] = packfrag(u0, u1);
      }
#pragma unroll
      for (int n = 0; n < 4; ++n)
        bfr[n] = *reinterpret_cast<const bf16x8*>(
            Bc + bcol + n * 2048 + ((ks * 64 + l4 * 16) ^ swB));
#pragma unroll
      for (int m = 0; m < 4; ++m)
#pragma unroll
        for (int n = 0; n < 4; ++n)
          acc[m][n] = __builtin_amdgcn_mfma_f32_16x16x32_bf16(af[m], bfr[n], acc[m][n], 0, 0, 0);
    }

    // chunk boundary: loads issued ~3200 cyc ago have landed; drain + barrier
    asm volatile("s_waitcnt vmcnt(0) lgkmcnt(0)" ::: "memory");
    __builtin_amdgcn_s_barrier();
  }
#undef STAGE_A
#undef STAGE_B

  __syncthreads();

  // ---- epilogue (R18-verified): activation -> LDS transpose (1040B pitch) ----
  float bs[4];
#pragma unroll
  for (int n = 0; n < 4; ++n) bs[n] = bias[wn * 64 + n * 16 + l15];

  const int rr2 = tid >> 5;            // 0..15 read-back row
  const int co = (tid & 31) * 8;       // read-back col (floats)
  const char* rdp = smem + rr2 * 1040 + co * 4;

#pragma unroll
  for (int p = 0; p < 8; ++p) {        // band p = rows p*16..+15 (wm group p>>2)
    if ((wid >> 2) == (p >> 2)) {
      const int m = p & 3;
#pragma unroll
      for (int n = 0; n < 4; ++n) {
        const int col = wn * 64 + n * 16 + l15;
        const bool diag = (col % 17) == 0;
#pragma unroll
        for (int j2 = 0; j2 < 4; ++j2) {
          const int rr = l4 * 4 + j2;
          float v = acc[m][n][j2] + bs[n];
          float e = __expf(-fabsf(v));
          float sig = (v >= 0.f) ? 1.f / (1.f + e) : e / (1.f + e);
          float sp = fmaxf(v, 0.f) + __logf(1.f + e);
          *reinterpret_cast<float*>(smem + rr * 1040 + col * 4) = diag ? sig : -sp;
        }
      }
    }
    __syncthreads();
    float4 o0 = *reinterpret_cast<const float4*>(rdp);
    float4 o1 = *reinterpret_cast<const float4*>(rdp + 16);
    float* orow = out + (blkRow + (size_t)(p * 16 + rr2)) * 256 + co;
    *reinterpret_cast<float4*>(orow) = o0;
    *reinterpret_cast<float4*>(orow + 4) = o1;
    __syncthreads();
  }
}

extern "C" void kernel_launch(void* const* d_in, const int* in_sizes, int n_in,
                              void* d_out, int out_size, void* d_ws, size_t ws_size,
                              hipStream_t stream) {
  const float* x = (const float*)d_in[0];
  const float* Wd = (const float*)d_in[1];
  const float* bd = (const float*)d_in[2];
  const float* Wo = (const float*)d_in[3];
  const float* bo = (const float*)d_in[4];
  float* out = (float*)d_out;
  char* wbuf = (char*)d_ws;                  // 512 KiB weight image
  float* bias = (float*)(wbuf + WBYTES);     // 1 KiB bias

  prep_kernel<<<dim3(256), dim3(256), 0, stream>>>(Wd, bd, Wo, bo, wbuf, bias);
  cap_main<<<dim3(512), dim3(THREADS), 0, stream>>>(x, wbuf, bias, out);
}

// Round 21
// 105.773 us; speedup vs baseline: 1.0551x; 1.0551x over previous
//
#include <hip/hip_runtime.h>
#include <hip/hip_bf16.h>
#include <stdint.h>

// C = (B,16,16): diag (k,k)=sigmoid(x·Wd[k]+bd[k]); off (i,j)=-softplus(x·Wo[r]+bo[r])
// Permuted GEMM out[b][c], c=i*16+j. M=65536 N=256 K=1024, bf16 MFMA 16x16x32.
// R21 = R18 machinery at 1024 thr / BM=256: B staged ONCE per CU (0.5 MB vs
// R18's 1.0) while keeping 16 waves of intra-block TLP (vs R19's 8). Per-CU
// lifetime vmem 2.05 -> 1.55 MB. A fp32 via gload_lds (3-slot ring of 32 KB,
// 2 insts/thread, pre-swizzled source); B via gload_lds (2-slot ring of 16 KB,
// 1 inst/thread). Per step: issue B(t+1), A(t+2); after MFMA wait vmcnt(2)
// (retire A(t+1)+B(t+1), keep A(t+2) in flight across raw barrier) — same
// per-wave counts as R17/R18. LDS 128 KB, 1 block/CU, launch_bounds(1024,4).

typedef __bf16 bf16x8 __attribute__((ext_vector_type(8)));
typedef float f32x4 __attribute__((ext_vector_type(4)));

#define THREADS 1024
#define BM 256
#define KSTEPS 32
#define WIMG 16384                 // per-K-step B image: 256 cols x 32 k x 2B
#define WBYTES (WIMG * KSTEPS)     // 512 KiB

#define ASLOT 32768                // A slot: 256 rows x 32 k x 4B fp32 (swizzled)
#define BBASE 98304                // A slots @0,32K,64K ; B slots @96K,112K
#define BSLOT 16384
#define SMEM_SZ 131072             // 128 KiB -> 1 block/CU

__device__ __forceinline__ unsigned bf_rtne(unsigned u) {
  return (u + 0x7fffu + ((u >> 16) & 1u)) >> 16;
}
__device__ __forceinline__ unsigned pack2(float lo, float hi) {
  return bf_rtne(__float_as_uint(lo)) | (bf_rtne(__float_as_uint(hi)) << 16);
}
// A-fragment pack: scalar casts -> compiler emits v_cvt_pk_bf16_f32 (RTNE)
__device__ __forceinline__ bf16x8 packfrag(const f32x4& a, const f32x4& b) {
  bf16x8 r;
  r[0] = (__bf16)a[0]; r[1] = (__bf16)a[1]; r[2] = (__bf16)a[2]; r[3] = (__bf16)a[3];
  r[4] = (__bf16)b[0]; r[5] = (__bf16)b[1]; r[6] = (__bf16)b[2]; r[7] = (__bf16)b[3];
  return r;
}
__device__ __forceinline__ void gload_lds16(const void* g, void* l) {
  __builtin_amdgcn_global_load_lds(
      (const __attribute__((address_space(1))) unsigned int*)g,
      (__attribute__((address_space(3))) unsigned int*)l, 16, 0, 0);
}

// B image per K-step (R4/R12-verified): byte(c,k)=(c*64+k*2)^(((c>>1)&3)<<4)
__global__ void prep_kernel(const float* __restrict__ Wd, const float* __restrict__ bd,
                            const float* __restrict__ Wo, const float* __restrict__ bo,
                            char* __restrict__ wbuf, float* __restrict__ bias) {
  const int c = blockIdx.x;    // 0..255 output col
  const int t = threadIdx.x;   // 0..255, 4 consecutive k each
  const int i = c >> 4, j = c & 15;
  const float* src;
  float b;
  if (i == j) { src = Wd + i * 1024; b = bd[i]; }
  else { int r = i * 15 + (j < i ? j : j - 1); src = Wo + r * 1024; b = bo[r]; }
  if (t == 0) bias[c] = b;
  const int kk = t * 4;
  const int img = kk >> 5, k5 = kk & 31;
  float4 v = *reinterpret_cast<const float4*>(src + kk);
  uint2 h;
  h.x = pack2(v.x, v.y);
  h.y = pack2(v.z, v.w);
  const unsigned off = (unsigned)((c * 64 + k5 * 2) ^ (((c >> 1) & 3) << 4));
  *reinterpret_cast<uint2*>(wbuf + img * WIMG + off) = h;
}

__global__ __launch_bounds__(THREADS, 4) void cap_main(
    const float* __restrict__ x, const char* __restrict__ wbuf,
    const float* __restrict__ bias, float* __restrict__ out) {
  __shared__ char smem[SMEM_SZ];

  const int tid = threadIdx.x;
  const int wid = tid >> 6;      // 0..15
  const int lane = tid & 63;
  const int l15 = lane & 15;
  const int l4 = lane >> 4;
  const int wm = wid >> 2;       // 0..3: rows wm*64..+63
  const int wn = wid & 3;        // 0..3: cols wn*64..+63

  const size_t blkRow = (size_t)blockIdx.x * BM;

  // ---- A staging map (2 insts/thread; 1024 thr x 16B x 2 = 32 KB slot) ----
  // inst i: row = i*128 + (tid>>3); col = (tid&7)*16 pre-swizzled by row&7;
  // dest = i*16384 + tid*16   (LDS byte(row,kb) = row*128 + (kb ^ ((row&7)<<4)))
  const unsigned acol = (unsigned)(((tid & 7) * 16) ^ (((tid >> 3) & 7) << 4));
  const char* asrc[2];
  unsigned adst[2];
#pragma unroll
  for (int i = 0; i < 2; ++i) {
    const int row = i * 128 + (tid >> 3);
    asrc[i] = (const char*)(x + (blkRow + (size_t)row) * 1024) + acol;
    adst[i] = (unsigned)(i * 16384 + tid * 16);
  }

  // ---- fragment read bases ----
  const unsigned swA = (unsigned)((l15 & 7) << 4);
  const unsigned bbase = (unsigned)(wn * 4096 + l15 * 64 +
                                    ((l4 * 16) ^ (((l15 >> 1) & 3) << 4)));

  f32x4 acc[4][4];
#pragma unroll
  for (int m = 0; m < 4; ++m)
#pragma unroll
    for (int n = 0; n < 4; ++n) acc[m][n] = (f32x4){0.f, 0.f, 0.f, 0.f};

#define STAGE_A(CH, SL)                                                        \
  {                                                                            \
    _Pragma("unroll") for (int i = 0; i < 2; ++i)                              \
        gload_lds16(asrc[i] + (CH) * 128, smem + (SL) + adst[i]);              \
  }
#define STAGE_B(CH, SL)                                                        \
  gload_lds16(wbuf + (CH) * WIMG + tid * 16,                                   \
              smem + BBASE + (SL) + tid * 16);

  // ---- prologue: A(0)[2], B(0)[1], A(1)[2]; vmcnt(2) retires A(0)+B(0) ----
  STAGE_A(0, 0);
  STAGE_B(0, 0);
  STAGE_A(1, ASLOT);
  asm volatile("s_waitcnt vmcnt(2)\n\ts_barrier" ::: "memory");

  unsigned aR = 0;          // A slot of step t (ring of 3)
  unsigned aI = 2 * ASLOT;  // A slot of step t+2
  unsigned bR = 0;          // B slot of step t (ring of 2)

  for (int t = 0; t < KSTEPS; ++t) {
    // issue B(t+1) first (retired this step), then A(t+2) (stays in flight)
    const int tb = (t + 1 < KSTEPS) ? t + 1 : KSTEPS - 1;
    STAGE_B(tb, bR ^ BSLOT);
    const int ta = (t + 2 < KSTEPS) ? t + 2 : KSTEPS - 1;
    STAGE_A(ta, aI);

    // fragments: A fp32 -> cvt_pk bf16; B bf16 direct
    const char* Ac = smem + aR;
    const char* Bc = smem + BBASE + bR;
    bf16x8 af[4], bfr[4];
#pragma unroll
    for (int m = 0; m < 4; ++m) {
      const unsigned rb = (unsigned)((wm * 64 + m * 16 + l15) * 128);
      f32x4 u0 = *reinterpret_cast<const f32x4*>(Ac + rb + ((l4 * 32) ^ swA));
      f32x4 u1 = *reinterpret_cast<const f32x4*>(Ac + rb + ((l4 * 32 + 16) ^ swA));
      af[m] = packfrag(u0, u1);
    }
#pragma unroll
    for (int n = 0; n < 4; ++n)
      bfr[n] = *reinterpret_cast<const bf16x8*>(Bc + bbase + n * 1024);

#pragma unroll
    for (int m = 0; m < 4; ++m)
#pragma unroll
      for (int n = 0; n < 4; ++n)
        acc[m][n] = __builtin_amdgcn_mfma_f32_16x16x32_bf16(af[m], bfr[n], acc[m][n], 0, 0, 0);

    // counted wait: retires B(t+1)+A(t+1); A(t+2)'s 2 insts stay in flight
    asm volatile("s_waitcnt vmcnt(2)" ::: "memory");
    asm volatile("s_waitcnt lgkmcnt(0)" ::: "memory");
    __builtin_amdgcn_s_barrier();

    // rotate rings
    aR = (aR == 2 * ASLOT) ? 0u : aR + ASLOT;
    aI = (aI == 2 * ASLOT) ? 0u : aI + ASLOT;
    bR ^= BSLOT;
  }
#undef STAGE_A
#undef STAGE_B

  // drain tail loads before reusing LDS
  asm volatile("s_waitcnt vmcnt(0)" ::: "memory");
  __syncthreads();

  // ---- epilogue: 16 bands of 16 rows; activation -> LDS transpose ----
  float bs[4];
#pragma unroll
  for (int n = 0; n < 4; ++n) bs[n] = bias[wn * 64 + n * 16 + l15];

  const int rr2 = tid >> 6;            // 0..15 read-back row
  const int cg = tid & 63;             // 4-float col group
  const char* rdp = smem + rr2 * 1040 + cg * 16;

#pragma unroll
  for (int p = 0; p < 16; ++p) {       // band p = rows p*16..+15 (wm = p>>2)
    if (wm == (p >> 2)) {
      const int m = p & 3;
#pragma unroll
      for (int n = 0; n < 4; ++n) {
        const int col = wn * 64 + n * 16 + l15;
        const bool diag = (col % 17) == 0;
#pragma unroll
        for (int j2 = 0; j2 < 4; ++j2) {
          const int rr = l4 * 4 + j2;
          float v = acc[m][n][j2] + bs[n];
          float e = __expf(-fabsf(v));
          float sig = (v >= 0.f) ? 1.f / (1.f + e) : e / (1.f + e);
          float sp = fmaxf(v, 0.f) + __logf(1.f + e);
          *reinterpret_cast<float*>(smem + rr * 1040 + col * 4) = diag ? sig : -sp;
        }
      }
    }
    __syncthreads();
    float4 o0 = *reinterpret_cast<const float4*>(rdp);
    float* orow = out + (blkRow + (size_t)(p * 16 + rr2)) * 256 + cg * 4;
    *reinterpret_cast<float4*>(orow) = o0;
    __syncthreads();
  }
}

extern "C" void kernel_launch(void* const* d_in, const int* in_sizes, int n_in,
                              void* d_out, int out_size, void* d_ws, size_t ws_size,
                              hipStream_t stream) {
  const float* x = (const float*)d_in[0];
  const float* Wd = (const float*)d_in[1];
  const float* bd = (const float*)d_in[2];
  const float* Wo = (const float*)d_in[3];
  const float* bo = (const float*)d_in[4];
  float* out = (float*)d_out;
  char* wbuf = (char*)d_ws;                  // 512 KiB weight image
  float* bias = (float*)(wbuf + WBYTES);     // 1 KiB bias

  prep_kernel<<<dim3(256), dim3(256), 0, stream>>>(Wd, bd, Wo, bo, wbuf, bias);
  cap_main<<<dim3(256), dim3(THREADS), 0, stream>>>(x, wbuf, bias, out);
}

// Round 22
// 98.462 us; speedup vs baseline: 1.1334x; 1.0743x over previous
//
#include <hip/hip_runtime.h>
#include <hip/hip_bf16.h>
#include <stdint.h>

// C = (B,16,16): diag (k,k)=sigmoid(x·Wd[k]+bd[k]); off (i,j)=-softplus(x·Wo[r]+bo[r])
// Permuted GEMM out[b][c], c=i*16+j. M=65536 N=256 K=1024, bf16 MFMA 16x16x32.
// R22 = R18 (best: 100.2 us) + swapped MFMA operands: mfma(W,x) puts 4
// CONSECUTIVE output cols in each lane (D: col=lane&15 -> x-row, row=l4*4+j ->
// W-col) -> activation + direct float4 stores, NO epilogue LDS transpose, no
// 16 epilogue barriers, no final drain round. Main loop identical to R18:
// BM=128, 512 blocks x 512 thr (8 waves 2Mx4N); A fp32 via gload_lds (3-slot
// ring, pre-swizzled source); B via gload_lds (2-slot ring); per step issue
// B(t+1), A(t+2), wait vmcnt(2) after MFMA; cvt_pk pack. LDS 80KB, 2 blk/CU.

typedef __bf16 bf16x8 __attribute__((ext_vector_type(8)));
typedef float f32x4 __attribute__((ext_vector_type(4)));

#define THREADS 512
#define BM 128
#define KSTEPS 32
#define WIMG 16384                 // per-K-step B image: 256 cols x 32 k x 2B
#define WBYTES (WIMG * KSTEPS)     // 512 KiB

#define ASLOT 16384                // A slot: 128 rows x 32 k x 4B fp32 (swizzled)
#define BBASE 49152                // A slots @0,16K,32K ; B slots @48K,64K
#define BSLOT 16384
#define SMEM_SZ 81920              // 80 KiB -> 2 blocks/CU

__device__ __forceinline__ unsigned bf_rtne(unsigned u) {
  return (u + 0x7fffu + ((u >> 16) & 1u)) >> 16;
}
__device__ __forceinline__ unsigned pack2(float lo, float hi) {
  return bf_rtne(__float_as_uint(lo)) | (bf_rtne(__float_as_uint(hi)) << 16);
}
// A-fragment pack: scalar casts -> compiler emits v_cvt_pk_bf16_f32 (RTNE)
__device__ __forceinline__ bf16x8 packfrag(const f32x4& a, const f32x4& b) {
  bf16x8 r;
  r[0] = (__bf16)a[0]; r[1] = (__bf16)a[1]; r[2] = (__bf16)a[2]; r[3] = (__bf16)a[3];
  r[4] = (__bf16)b[0]; r[5] = (__bf16)b[1]; r[6] = (__bf16)b[2]; r[7] = (__bf16)b[3];
  return r;
}
__device__ __forceinline__ void gload_lds16(const void* g, void* l) {
  __builtin_amdgcn_global_load_lds(
      (const __attribute__((address_space(1))) unsigned int*)g,
      (__attribute__((address_space(3))) unsigned int*)l, 16, 0, 0);
}

// B image per K-step (R4/R12-verified): byte(c,k)=(c*64+k*2)^(((c>>1)&3)<<4)
__global__ void prep_kernel(const float* __restrict__ Wd, const float* __restrict__ bd,
                            const float* __restrict__ Wo, const float* __restrict__ bo,
                            char* __restrict__ wbuf, float* __restrict__ bias) {
  const int c = blockIdx.x;    // 0..255 output col
  const int t = threadIdx.x;   // 0..255, 4 consecutive k each
  const int i = c >> 4, j = c & 15;
  const float* src;
  float b;
  if (i == j) { src = Wd + i * 1024; b = bd[i]; }
  else { int r = i * 15 + (j < i ? j : j - 1); src = Wo + r * 1024; b = bo[r]; }
  if (t == 0) bias[c] = b;
  const int kk = t * 4;
  const int img = kk >> 5, k5 = kk & 31;
  float4 v = *reinterpret_cast<const float4*>(src + kk);
  uint2 h;
  h.x = pack2(v.x, v.y);
  h.y = pack2(v.z, v.w);
  const unsigned off = (unsigned)((c * 64 + k5 * 2) ^ (((c >> 1) & 3) << 4));
  *reinterpret_cast<uint2*>(wbuf + img * WIMG + off) = h;
}

__global__ __launch_bounds__(THREADS, 4) void cap_main(
    const float* __restrict__ x, const char* __restrict__ wbuf,
    const float* __restrict__ bias, float* __restrict__ out) {
  __shared__ char smem[SMEM_SZ];

  const int tid = threadIdx.x;
  const int wid = tid >> 6;
  const int lane = tid & 63;
  const int l15 = lane & 15;
  const int l4 = lane >> 4;
  const int wm = wid >> 2;       // 0..1: rows wm*64..+63
  const int wn = wid & 3;        // 0..3: cols wn*64..+63

  const size_t blkRow = (size_t)blockIdx.x * BM;

  // ---- A staging map (2 insts/thread; 512 thr x 16B x 2 = 16 KB slot) ----
  const unsigned acol = (unsigned)(((tid & 7) * 16) ^ (((tid >> 3) & 7) << 4));
  const char* asrc[2];
  unsigned adst[2];
#pragma unroll
  for (int i = 0; i < 2; ++i) {
    const int row = i * 64 + (tid >> 3);
    asrc[i] = (const char*)(x + (blkRow + (size_t)row) * 1024) + acol;
    adst[i] = (unsigned)(i * 8192 + tid * 16);
  }

  // ---- fragment read bases ----
  const unsigned swA = (unsigned)((l15 & 7) << 4);
  const unsigned bbase = (unsigned)(wn * 4096 + l15 * 64 +
                                    ((l4 * 16) ^ (((l15 >> 1) & 3) << 4)));

  f32x4 acc[4][4];
#pragma unroll
  for (int m = 0; m < 4; ++m)
#pragma unroll
    for (int n = 0; n < 4; ++n) acc[m][n] = (f32x4){0.f, 0.f, 0.f, 0.f};

#define STAGE_A(CH, SL)                                                        \
  {                                                                            \
    _Pragma("unroll") for (int i = 0; i < 2; ++i)                              \
        gload_lds16(asrc[i] + (CH) * 128, smem + (SL) + adst[i]);              \
  }
#define STAGE_B(CH, SL)                                                        \
  {                                                                            \
    const char* wsp = wbuf + (CH) * WIMG;                                      \
    _Pragma("unroll") for (int i = 0; i < 2; ++i)                              \
        gload_lds16(wsp + i * 8192 + tid * 16,                                 \
                    smem + BBASE + (SL) + i * 8192 + tid * 16);                \
  }

  // ---- prologue: A(0), B(0), A(1); vmcnt(2) retires A(0)+B(0) ----
  STAGE_A(0, 0);
  STAGE_B(0, 0);
  STAGE_A(1, ASLOT);
  asm volatile("s_waitcnt vmcnt(2)\n\ts_barrier" ::: "memory");

  unsigned aR = 0;          // A slot of step t (ring of 3)
  unsigned aI = 2 * ASLOT;  // A slot of step t+2
  unsigned bR = 0;          // B slot of step t (ring of 2)

  for (int t = 0; t < KSTEPS; ++t) {
    // issue B(t+1) first (retired this step), then A(t+2) (stays in flight)
    const int tb = (t + 1 < KSTEPS) ? t + 1 : KSTEPS - 1;
    STAGE_B(tb, bR ^ BSLOT);
    const int ta = (t + 2 < KSTEPS) ? t + 2 : KSTEPS - 1;
    STAGE_A(ta, aI);

    // fragments: A fp32 -> cvt_pk bf16; B bf16 direct
    const char* Ac = smem + aR;
    const char* Bc = smem + BBASE + bR;
    bf16x8 af[4], bfr[4];
#pragma unroll
    for (int m = 0; m < 4; ++m) {
      const unsigned rb = (unsigned)((wm * 64 + m * 16 + l15) * 128);
      f32x4 u0 = *reinterpret_cast<const f32x4*>(Ac + rb + ((l4 * 32) ^ swA));
      f32x4 u1 = *reinterpret_cast<const f32x4*>(Ac + rb + ((l4 * 32 + 16) ^ swA));
      af[m] = packfrag(u0, u1);
    }
#pragma unroll
    for (int n = 0; n < 4; ++n)
      bfr[n] = *reinterpret_cast<const bf16x8*>(Bc + bbase + n * 1024);

    // SWAPPED operands: D col(lane&15)=x-row, D row(l4*4+j)=W-col
#pragma unroll
    for (int m = 0; m < 4; ++m)
#pragma unroll
      for (int n = 0; n < 4; ++n)
        acc[m][n] = __builtin_amdgcn_mfma_f32_16x16x32_bf16(bfr[n], af[m], acc[m][n], 0, 0, 0);

    // counted wait: retires B(t+1)+A(t+1); A(t+2)'s 2 insts stay in flight
    asm volatile("s_waitcnt vmcnt(2)" ::: "memory");
    asm volatile("s_waitcnt lgkmcnt(0)" ::: "memory");
    __builtin_amdgcn_s_barrier();

    // rotate rings
    aR = (aR == 2 * ASLOT) ? 0u : aR + ASLOT;
    aI = (aI == 2 * ASLOT) ? 0u : aI + ASLOT;
    bR ^= BSLOT;
  }
#undef STAGE_A
#undef STAGE_B

  // ---- epilogue: bias + activation + DIRECT float4 stores (no LDS, no sync) ----
  // lane holds out[blkRow + wm*64 + m*16 + l15][wn*64 + n*16 + l4*4 + j], j=0..3
#pragma unroll
  for (int n = 0; n < 4; ++n) {
    const int colb = wn * 64 + n * 16 + l4 * 4;
    const float4 bb = *reinterpret_cast<const float4*>(bias + colb);
    const bool d0 = ((colb + 0) % 17) == 0;
    const bool d1 = ((colb + 1) % 17) == 0;
    const bool d2 = ((colb + 2) % 17) == 0;
    const bool d3 = ((colb + 3) % 17) == 0;
#pragma unroll
    for (int m = 0; m < 4; ++m) {
      const size_t row = blkRow + (size_t)(wm * 64 + m * 16 + l15);
      float4 o;
#pragma unroll
      for (int j2 = 0; j2 < 4; ++j2) {
        float v = acc[m][n][j2] + (&bb.x)[j2];
        float e = __expf(-fabsf(v));
        float sig = (v >= 0.f) ? 1.f / (1.f + e) : e / (1.f + e);
        float sp = fmaxf(v, 0.f) + __logf(1.f + e);
        const bool diag = j2 == 0 ? d0 : j2 == 1 ? d1 : j2 == 2 ? d2 : d3;
        (&o.x)[j2] = diag ? sig : -sp;
      }
      *reinterpret_cast<float4*>(out + row * 256 + colb) = o;
    }
  }
}

extern "C" void kernel_launch(void* const* d_in, const int* in_sizes, int n_in,
                              void* d_out, int out_size, void* d_ws, size_t ws_size,
                              hipStream_t stream) {
  const float* x = (const float*)d_in[0];
  const float* Wd = (const float*)d_in[1];
  const float* bd = (const float*)d_in[2];
  const float* Wo = (const float*)d_in[3];
  const float* bo = (const float*)d_in[4];
  float* out = (float*)d_out;
  char* wbuf = (char*)d_ws;                  // 512 KiB weight image
  float* bias = (float*)(wbuf + WBYTES);     // 1 KiB bias

  prep_kernel<<<dim3(256), dim3(256), 0, stream>>>(Wd, bd, Wo, bo, wbuf, bias);
  cap_main<<<dim3(512), dim3(THREADS), 0, stream>>>(x, wbuf, bias, out);
}